// Round 9
// baseline (258.253 us; speedup 1.0000x reference)
//
#include <hip/hip_runtime.h>
#include <hip/hip_bf16.h>
#include <stdint.h>

typedef __bf16 bf16x8 __attribute__((ext_vector_type(8)));
typedef float f32x4 __attribute__((ext_vector_type(4)));

#define LOG2E 1.44269504088896340736f

__device__ inline void gload_lds16(const void* g, void* l) {
  __builtin_amdgcn_global_load_lds((const __attribute__((address_space(1))) void*)g,
                                   (__attribute__((address_space(3))) void*)l, 16, 0, 0);
}

__device__ inline unsigned short bf16_bits(float f) {
  return __builtin_bit_cast(unsigned short, __float2bfloat16(f));
}

// pack two f32 -> one u32 of 2 bf16 (low = first arg)
__device__ inline uint32_t cvtpk_bf16(float lo, float hi) {
  uint32_t d;
  asm("v_cvt_pk_bf16_f32 %0, %1, %2" : "=v"(d) : "v"(lo), "v"(hi));
  return d;
}
// gfx950 cross-lane row swaps: a.rows[32:63] <-> b.rows[0:31]
__device__ inline void plswap32(uint32_t& a, uint32_t& b) {
  asm("v_permlane32_swap_b32 %0, %1" : "+v"(a), "+v"(b));
}
// a.rows[16:31] <-> b.rows[0:15], a.rows[48:63] <-> b.rows[32:47]
__device__ inline void plswap16(uint32_t& a, uint32_t& b) {
  asm("v_permlane16_swap_b32 %0, %1" : "+v"(a), "+v"(b));
}

// ---------------- LayerNorm: x[8192][1024] f32 -> xn bf16 ----------------
__global__ __launch_bounds__(256) void ln_kernel(
    const float* __restrict__ x, const float* __restrict__ gamma,
    const float* __restrict__ beta, __hip_bfloat16* __restrict__ xn)
{
  const int row = blockIdx.x;
  const int t = threadIdx.x;
  const float4 v = reinterpret_cast<const float4*>(x + (size_t)row * 1024)[t];
  float s = v.x + v.y + v.z + v.w;
  float q = v.x*v.x + v.y*v.y + v.z*v.z + v.w*v.w;
  #pragma unroll
  for (int off = 32; off >= 1; off >>= 1) {
    s += __shfl_xor(s, off);
    q += __shfl_xor(q, off);
  }
  __shared__ float ls[4], lq[4];
  const int wave = t >> 6, lane = t & 63;
  if (lane == 0) { ls[wave] = s; lq[wave] = q; }
  __syncthreads();
  s = ls[0] + ls[1] + ls[2] + ls[3];
  q = lq[0] + lq[1] + lq[2] + lq[3];
  const float mean = s * (1.0f/1024.0f);
  const float var  = q * (1.0f/1024.0f) - mean*mean;
  const float rstd = rsqrtf(var + 1e-6f);
  const float4 gm = reinterpret_cast<const float4*>(gamma)[t];
  const float4 bt = reinterpret_cast<const float4*>(beta)[t];
  ushort4 o;
  o.x = bf16_bits((v.x - mean)*rstd*gm.x + bt.x);
  o.y = bf16_bits((v.y - mean)*rstd*gm.y + bt.y);
  o.z = bf16_bits((v.z - mean)*rstd*gm.z + bt.z);
  o.w = bf16_bits((v.w - mean)*rstd*gm.w + bt.w);
  reinterpret_cast<ushort4*>(xn + (size_t)row*1024)[t] = o;
}

// ---------------- f32 -> bf16 convert (1M elements per launch) ----------------
__global__ __launch_bounds__(256) void cvt_kernel(const float* __restrict__ src,
                                                  __hip_bfloat16* __restrict__ dst)
{
  const int i = blockIdx.x * 256 + threadIdx.x;
  const float4 v = reinterpret_cast<const float4*>(src)[i];
  ushort4 o;
  o.x = bf16_bits(v.x); o.y = bf16_bits(v.y);
  o.z = bf16_bits(v.z); o.w = bf16_bits(v.w);
  reinterpret_cast<ushort4*>(dst)[i] = o;
}

// ---------------- NT-GEMM: C[M][N] = A[M][K] * B[N][K]^T, K=1024 ----------------
// 128x128 tile, 4 waves (2x2 of 64x64), BK=32.
// T4 upgrade: double-buffered LDS + raw s_barrier + COUNTED s_waitcnt vmcnt(4):
// next tile's 4 global_load_lds stay in flight across both barriers (no
// vmcnt(0) drain -- the documented ~20% m97 stall). XCD-chunked swizzle.
template<int MODE>
__global__ __launch_bounds__(256) void gemm_bt(
    const __hip_bfloat16* __restrict__ A,
    const __hip_bfloat16* __restrict__ B,
    const float* __restrict__ bias0,
    const float* __restrict__ bias1,
    void* __restrict__ C0,
    void* __restrict__ C1)
{
  constexpr int K = 1024;
  __shared__ __align__(16) __hip_bfloat16 Al[2][128*32];
  __shared__ __align__(16) __hip_bfloat16 Bl[2][128*32];
  const int t = threadIdx.x;
  const int wave = t >> 6, lane = t & 63;
  const int li = lane & 15, g = lane >> 4;
  const int wm = (wave >> 1) * 64, wn = (wave & 1) * 64;

  // XCD swizzle: each XCD gets a contiguous chunk of the logical grid
  const int lin = blockIdx.y * gridDim.x + blockIdx.x;
  const int cpx = (gridDim.x * gridDim.y) >> 3;
  const int wg  = (lin & 7) * cpx + (lin >> 3);
  const int bx  = wg & (gridDim.x - 1);
  const int by  = wg >> __builtin_ctz(gridDim.x);

  const int m0 = by * 128, n0 = bx * 128;
  const int srow = t >> 2, sch = (t & 3) * 8;

  const __hip_bfloat16* ga = A + (size_t)(m0 + srow) * K + sch;
  const __hip_bfloat16* gb = B + (size_t)(n0 + srow) * K + sch;

  // stage K-step kt into buffer buf (4 loads, 4 vmcnt units per wave)
  auto stage = [&](int buf, int kt) {
    gload_lds16(ga + kt,        &Al[buf][t*8]);
    gload_lds16(ga + kt + 64*K, &Al[buf][t*8 + 2048]);
    gload_lds16(gb + kt,        &Bl[buf][t*8]);
    gload_lds16(gb + kt + 64*K, &Bl[buf][t*8 + 2048]);
  };

  f32x4 acc[4][4] = {};

  // prologue: tiles 0 and 1 in flight; wait only tile 0 (oldest 4)
  stage(0, 0);
  stage(1, 32);
  asm volatile("s_waitcnt vmcnt(4)" ::: "memory");
  __builtin_amdgcn_sched_barrier(0);
  __builtin_amdgcn_s_barrier();

  for (int it = 0; it < 32; ++it) {
    const int cur = it & 1;
    const __hip_bfloat16* Ab = Al[cur];
    const __hip_bfloat16* Bb = Bl[cur];
    bf16x8 af[4], bfr[4];
    #pragma unroll
    for (int mi = 0; mi < 4; ++mi)
      af[mi] = *reinterpret_cast<const bf16x8*>(&Ab[(wm + mi*16 + li)*32 + g*8]);
    #pragma unroll
    for (int ni = 0; ni < 4; ++ni)
      bfr[ni] = *reinterpret_cast<const bf16x8*>(&Bb[(wn + ni*16 + li)*32 + g*8]);
    __builtin_amdgcn_s_setprio(1);
    #pragma unroll
    for (int mi = 0; mi < 4; ++mi)
      #pragma unroll
      for (int ni = 0; ni < 4; ++ni)
        acc[mi][ni] = __builtin_amdgcn_mfma_f32_16x16x32_bf16(af[mi], bfr[ni], acc[mi][ni], 0, 0, 0);
    __builtin_amdgcn_s_setprio(0);

    // all waves finished reading buf[cur] (their reads were consumed by MFMA)
    __builtin_amdgcn_s_barrier();

    if (it < 30) {
      stage(cur, (it + 2) * 32);                       // overwrite consumed buffer
      asm volatile("s_waitcnt vmcnt(4)" ::: "memory"); // tile it+1 landed; it+2 in flight
    } else {
      asm volatile("s_waitcnt vmcnt(0)" ::: "memory"); // tail: drain last tile
    }
    __builtin_amdgcn_sched_barrier(0);
    __builtin_amdgcn_s_barrier();                      // all waves' next tile visible
  }

  #pragma unroll
  for (int mi = 0; mi < 4; ++mi) {
    #pragma unroll
    for (int ni = 0; ni < 4; ++ni) {
      #pragma unroll
      for (int r = 0; r < 4; ++r) {
        const int grow = m0 + wm + mi*16 + g*4 + r;
        const int gcol = n0 + wn + ni*16 + li;
        float v = acc[mi][ni][r];
        if constexpr (MODE == 0) {
          const int b = grow >> 11, ss = grow & 2047;
          if (gcol < 1024) {
            // fold 1/sqrt(hd) AND log2(e) into Q so attn uses exp2 directly
            v = (v + bias0[gcol]) * (0.125f * LOG2E);
            const int h = gcol >> 6, d = gcol & 63;
            ((__hip_bfloat16*)C0)[(((size_t)(b*16 + h))*2048 + ss)*64 + d] = __float2bfloat16(v);
          } else {
            const int c2 = gcol - 1024;
            v = v + bias1[c2];
            const int h = c2 >> 6, d = c2 & 63;
            ((__hip_bfloat16*)C1)[(((size_t)(b*16 + h))*2048 + ss)*64 + d] = __float2bfloat16(v);
          }
        } else if constexpr (MODE == 1) {
          v += bias0[grow];
          ((__hip_bfloat16*)C0)[(size_t)grow*8192 + gcol] = __float2bfloat16(v);
        } else {
          v += bias0[gcol];
          ((float*)C0)[(size_t)grow*1024 + gcol] = v;
        }
      }
    }
  }
}

// ---------------- Flash attention (in-register P: cvt_pk + permlane swaps) -------
// grid 1024 blocks x 256 threads = 4 waves; wave owns 32 q-rows (2 x 16-row subtiles).
// Q: [bh][s][64] bf16 pre-scaled by 0.125*log2(e). K: [bh][s][64]. Vt: [1024][8192].
// Zero-max softmax (scores bounded; |s| << exp2 overflow).
// P never touches LDS (cvt_pk + permlane32/16_swap redistribution).
// LDS = 32 KB (K/V dbuf only). SQ_LDS_BANK_CONFLICT = 0 (R8 measured).
__global__ __launch_bounds__(256, 4) void attn_kernel(
    const __hip_bfloat16* __restrict__ Q,
    const __hip_bfloat16* __restrict__ K,
    const __hip_bfloat16* __restrict__ Vt,
    __hip_bfloat16* __restrict__ ctx)
{
  const int t = threadIdx.x, wave = t >> 6, lane = t & 63;
  const int li = lane & 15, g = lane >> 4;

  // XCD-chunked decode: 1024 blocks, 128 per XCD = 8 bh per XCD
  const int lin = blockIdx.x;
  const int wg  = (lin & 7) * 128 + (lin >> 3);
  const int bh  = wg >> 4, qt = wg & 15;
  const int b = bh >> 4, h = bh & 15;
  const int qbase = qt * 128 + wave * 32;

  __shared__ __align__(16) __hip_bfloat16 Klds[2][4096];  // 16 KB
  __shared__ __align__(16) __hip_bfloat16 Vlds[2][4096];  // 16 KB

  const bf16x8* Qv0 = reinterpret_cast<const bf16x8*>(Q + ((size_t)bh*2048 + qbase + li)*64 + g*8);
  const bf16x8* Qv1 = reinterpret_cast<const bf16x8*>(Q + ((size_t)bh*2048 + qbase + 16 + li)*64 + g*8);
  const bf16x8 aQ00 = Qv0[0], aQ01 = Qv0[4];
  const bf16x8 aQ10 = Qv1[0], aQ11 = Qv1[4];

  f32x4 acc0[4] = {}, acc1[4] = {};
  float l0 = 0.f, l1 = 0.f;   // per-lane partial sums (q = li of each subtile)

  const __hip_bfloat16* Kbh = K + (size_t)bh*2048*64;
  const __hip_bfloat16* Vbh = Vt + (size_t)h*64*8192 + b*2048;

  // staging: 256 threads x 2 chunks cover 64 rows x 128B; swizzle byte ^= (row&7)<<4
  // pre-applied on the GLOBAL source (linear LDS dest, rule #21)
  const int l8 = lane >> 3;
  const int scb_e = ((((lane & 7) * 16) ^ (l8 << 4)) >> 1);  // elements
  const int row0 = wave * 8 + l8;

  // ds_read offsets (elements), swizzle applied on read
  const int krd0 = (li*128 + ((g*16)      ^ ((li & 7) << 4))) >> 1;
  const int krd1 = (li*128 + ((g*16 + 64) ^ ((li & 7) << 4))) >> 1;

  // prologue: stage tile 0 into buffer 0
  gload_lds16(Kbh + (size_t)row0*64 + scb_e,        &Klds[0][wave*512]);
  gload_lds16(Kbh + (size_t)(32+row0)*64 + scb_e,   &Klds[0][2048 + wave*512]);
  gload_lds16(Vbh + (size_t)row0*8192 + scb_e,      &Vlds[0][wave*512]);
  gload_lds16(Vbh + (size_t)(32+row0)*8192 + scb_e, &Vlds[0][2048 + wave*512]);
  __syncthreads();

  const __hip_bfloat16* kSrc = Kbh + (size_t)(64 + row0)*64 + scb_e;
  const __hip_bfloat16* vSrc = Vbh + (size_t)row0*8192 + 64 + scb_e;

  int cur = 0;
  for (int it = 0; it < 32; ++it) {
    if (it < 31) {
      __hip_bfloat16* kD = Klds[cur^1];
      __hip_bfloat16* vD = Vlds[cur^1];
      gload_lds16(kSrc,           kD + wave*512);
      gload_lds16(kSrc + 32*64,   kD + 2048 + wave*512);
      gload_lds16(vSrc,           vD + wave*512);
      gload_lds16(vSrc + 32*8192, vD + 2048 + wave*512);
      kSrc += 64*64;
      vSrc += 64;
    }

    const __hip_bfloat16* Kc = Klds[cur];
    const __hip_bfloat16* Vc = Vlds[cur];

    // QK^T swapped, both subtiles per K-frag read:
    // s_u[nt] holds S[k=nt*16+g*4+r][q=li] for subtile u
    f32x4 s0[4] = {}, s1[4] = {};
    __builtin_amdgcn_s_setprio(1);
    #pragma unroll
    for (int nt = 0; nt < 4; ++nt) {
      const bf16x8 k0 = *reinterpret_cast<const bf16x8*>(&Kc[nt*1024 + krd0]);
      const bf16x8 k1 = *reinterpret_cast<const bf16x8*>(&Kc[nt*1024 + krd1]);
      s0[nt] = __builtin_amdgcn_mfma_f32_16x16x32_bf16(k0, aQ00, s0[nt], 0, 0, 0);
      s0[nt] = __builtin_amdgcn_mfma_f32_16x16x32_bf16(k1, aQ01, s0[nt], 0, 0, 0);
      s1[nt] = __builtin_amdgcn_mfma_f32_16x16x32_bf16(k0, aQ10, s1[nt], 0, 0, 0);
      s1[nt] = __builtin_amdgcn_mfma_f32_16x16x32_bf16(k1, aQ11, s1[nt], 0, 0, 0);
    }
    __builtin_amdgcn_s_setprio(0);

    // zero-max softmax: p = exp2(s); per-lane partial l
    float sm0 = 0.f, sm1 = 0.f;
    #pragma unroll
    for (int nt = 0; nt < 4; ++nt)
      #pragma unroll
      for (int r = 0; r < 4; ++r) {
        const float p0 = exp2f(s0[nt][r]); s0[nt][r] = p0; sm0 += p0;
        const float p1 = exp2f(s1[nt][r]); s1[nt][r] = p1; sm1 += p1;
      }
    l0 += sm0; l1 += sm1;

    // ---- in-register P redistribution (per subtile):
    // c[nt][w] = bf16 pair for k = nt*16 + g*4 + 2w.
    // banks (0,1) -> aP_lo (k = g*8+j), banks (2,3) -> aP_hi (k = 32+g*8+j)
    union U8 { uint32_t w[4]; bf16x8 v; };
    bf16x8 aP00, aP01, aP10, aP11;
    {
      uint32_t c[4][2];
      #pragma unroll
      for (int nt = 0; nt < 4; ++nt) {
        c[nt][0] = cvtpk_bf16(s0[nt][0], s0[nt][1]);
        c[nt][1] = cvtpk_bf16(s0[nt][2], s0[nt][3]);
      }
      uint32_t x0 = c[0][0], y0 = c[1][0], x1 = c[0][1], y1 = c[1][1];
      plswap32(x0, y0); plswap32(x1, y1);
      plswap16(x0, y0); plswap16(x1, y1);
      U8 u0; u0.w[0] = x0; u0.w[1] = x1; u0.w[2] = y0; u0.w[3] = y1;
      aP00 = u0.v;
      uint32_t x2 = c[2][0], y2 = c[3][0], x3 = c[2][1], y3 = c[3][1];
      plswap32(x2, y2); plswap32(x3, y3);
      plswap16(x2, y2); plswap16(x3, y3);
      U8 u1; u1.w[0] = x2; u1.w[1] = x3; u1.w[2] = y2; u1.w[3] = y3;
      aP01 = u1.v;
    }
    {
      uint32_t c[4][2];
      #pragma unroll
      for (int nt = 0; nt < 4; ++nt) {
        c[nt][0] = cvtpk_bf16(s1[nt][0], s1[nt][1]);
        c[nt][1] = cvtpk_bf16(s1[nt][2], s1[nt][3]);
      }
      uint32_t x0 = c[0][0], y0 = c[1][0], x1 = c[0][1], y1 = c[1][1];
      plswap32(x0, y0); plswap32(x1, y1);
      plswap16(x0, y0); plswap16(x1, y1);
      U8 u0; u0.w[0] = x0; u0.w[1] = x1; u0.w[2] = y0; u0.w[3] = y1;
      aP10 = u0.v;
      uint32_t x2 = c[2][0], y2 = c[3][0], x3 = c[2][1], y3 = c[3][1];
      plswap32(x2, y2); plswap32(x3, y3);
      plswap16(x2, y2); plswap16(x3, y3);
      U8 u1; u1.w[0] = x2; u1.w[1] = x3; u1.w[2] = y2; u1.w[3] = y3;
      aP11 = u1.v;
    }

    // PV swapped, both subtiles per V-frag read
    __builtin_amdgcn_s_setprio(1);
    #pragma unroll
    for (int dt = 0; dt < 4; ++dt) {
      const bf16x8 v0 = *reinterpret_cast<const bf16x8*>(&Vc[dt*1024 + krd0]);
      const bf16x8 v1 = *reinterpret_cast<const bf16x8*>(&Vc[dt*1024 + krd1]);
      acc0[dt] = __builtin_amdgcn_mfma_f32_16x16x32_bf16(v0, aP00, acc0[dt], 0, 0, 0);
      acc0[dt] = __builtin_amdgcn_mfma_f32_16x16x32_bf16(v1, aP01, acc0[dt], 0, 0, 0);
      acc1[dt] = __builtin_amdgcn_mfma_f32_16x16x32_bf16(v0, aP10, acc1[dt], 0, 0, 0);
      acc1[dt] = __builtin_amdgcn_mfma_f32_16x16x32_bf16(v1, aP11, acc1[dt], 0, 0, 0);
    }
    __builtin_amdgcn_s_setprio(0);

    // barrier drains vmcnt (staged tile complete) + syncs buffer reuse
    __syncthreads();
    cur ^= 1;
  }

  // reduce l across the 4 g-groups (same q=li)
  l0 += __shfl_xor(l0, 16); l0 += __shfl_xor(l0, 32);
  l1 += __shfl_xor(l1, 16); l1 += __shfl_xor(l1, 32);
  const float inv0 = 1.0f / l0;
  const float inv1 = 1.0f / l1;

  __hip_bfloat16* cp = ctx + ((size_t)(b*2048 + qbase))*1024 + h*64;
  #pragma unroll
  for (int dt = 0; dt < 4; ++dt) {
    ushort4 o0, o1;
    o0.x = bf16_bits(acc0[dt][0] * inv0);
    o0.y = bf16_bits(acc0[dt][1] * inv0);
    o0.z = bf16_bits(acc0[dt][2] * inv0);
    o0.w = bf16_bits(acc0[dt][3] * inv0);
    *reinterpret_cast<ushort4*>(&cp[(size_t)li*1024 + dt*16 + g*4]) = o0;
    o1.x = bf16_bits(acc1[dt][0] * inv1);
    o1.y = bf16_bits(acc1[dt][1] * inv1);
    o1.z = bf16_bits(acc1[dt][2] * inv1);
    o1.w = bf16_bits(acc1[dt][3] * inv1);
    *reinterpret_cast<ushort4*>(&cp[(size_t)(16 + li)*1024 + dt*16 + g*4]) = o1;
  }
}

extern "C" void kernel_launch(void* const* d_in, const int* in_sizes, int n_in,
                              void* d_out, int out_size, void* d_ws, size_t ws_size,
                              hipStream_t stream)
{
  const float* x  = (const float*)d_in[0];
  const float* g  = (const float*)d_in[1];
  const float* be = (const float*)d_in[2];
  const float* Wq = (const float*)d_in[3];
  const float* bq = (const float*)d_in[4];
  const float* Wk = (const float*)d_in[5];
  const float* bk = (const float*)d_in[6];
  const float* Wv = (const float*)d_in[7];
  const float* bv = (const float*)d_in[8];
  const float* Wo = (const float*)d_in[9];
  const float* bo = (const float*)d_in[10];
  float* out = (float*)d_out;

  char* ws = (char*)d_ws;
  __hip_bfloat16* xn  = (__hip_bfloat16*)(ws);              // 16 MB
  __hip_bfloat16* Wqk = (__hip_bfloat16*)(ws + 16777216);   // 4 MB  [2048][1024]
  __hip_bfloat16* Wvb = (__hip_bfloat16*)(ws + 20971520);   // 2 MB
  __hip_bfloat16* Wob = (__hip_bfloat16*)(ws + 23068672);   // 2 MB
  __hip_bfloat16* Qb  = (__hip_bfloat16*)(ws + 25165824);   // 16 MB [bh][s][64]
  __hip_bfloat16* Kb  = (__hip_bfloat16*)(ws + 41943040);   // 16 MB
  __hip_bfloat16* Vt  = (__hip_bfloat16*)(ws + 58720256);   // 16 MB [1024][8192]
  __hip_bfloat16* ctx = (__hip_bfloat16*)(ws + 75497472);   // 16 MB [8192][1024]

  ln_kernel<<<8192, 256, 0, stream>>>(x, g, be, xn);
  cvt_kernel<<<1024, 256, 0, stream>>>(Wq, Wqk);
  cvt_kernel<<<1024, 256, 0, stream>>>(Wk, Wqk + 1024*1024);
  cvt_kernel<<<1024, 256, 0, stream>>>(Wv, Wvb);
  cvt_kernel<<<1024, 256, 0, stream>>>(Wo, Wob);

  // Q,K projections: [8192 x 2048] = xn @ [Wq;Wk]^T
  gemm_bt<0><<<dim3(16, 64), 256, 0, stream>>>(xn, Wqk, bq, bk, Qb, Kb);
  // V^T: [1024 x 8192] = Wv @ xn^T  (NT with A=Wv, B=xn)
  gemm_bt<1><<<dim3(64, 8), 256, 0, stream>>>(Wvb, xn, bv, nullptr, Vt, nullptr);
  // attention: 1024 blocks x 256 threads (4 waves x 32 q-rows)
  attn_kernel<<<1024, 256, 0, stream>>>(Qb, Kb, Vt, ctx);
  // output projection: [8192 x 1024] = ctx @ Wo^T + bo (f32 out)
  gemm_bt<2><<<dim3(8, 64), 256, 0, stream>>>(ctx, Wob, bo, nullptr, out, nullptr);
}

// Round 10
// 256.186 us; speedup vs baseline: 1.0081x; 1.0081x over previous
//
#include <hip/hip_runtime.h>
#include <hip/hip_bf16.h>
#include <stdint.h>

typedef __bf16 bf16x8 __attribute__((ext_vector_type(8)));
typedef float f32x4 __attribute__((ext_vector_type(4)));

#define LOG2E 1.44269504088896340736f

__device__ inline void gload_lds16(const void* g, void* l) {
  __builtin_amdgcn_global_load_lds((const __attribute__((address_space(1))) void*)g,
                                   (__attribute__((address_space(3))) void*)l, 16, 0, 0);
}

__device__ inline unsigned short bf16_bits(float f) {
  return __builtin_bit_cast(unsigned short, __float2bfloat16(f));
}

// pack two f32 -> one u32 of 2 bf16 (low = first arg)
__device__ inline uint32_t cvtpk_bf16(float lo, float hi) {
  uint32_t d;
  asm("v_cvt_pk_bf16_f32 %0, %1, %2" : "=v"(d) : "v"(lo), "v"(hi));
  return d;
}
// gfx950 cross-lane row swaps: a.rows[32:63] <-> b.rows[0:31]
__device__ inline void plswap32(uint32_t& a, uint32_t& b) {
  asm("v_permlane32_swap_b32 %0, %1" : "+v"(a), "+v"(b));
}
// a.rows[16:31] <-> b.rows[0:15], a.rows[48:63] <-> b.rows[32:47]
__device__ inline void plswap16(uint32_t& a, uint32_t& b) {
  asm("v_permlane16_swap_b32 %0, %1" : "+v"(a), "+v"(b));
}

// ---------------- LayerNorm: x[8192][1024] f32 -> xn bf16 ----------------
__global__ __launch_bounds__(256) void ln_kernel(
    const float* __restrict__ x, const float* __restrict__ gamma,
    const float* __restrict__ beta, __hip_bfloat16* __restrict__ xn)
{
  const int row = blockIdx.x;
  const int t = threadIdx.x;
  const float4 v = reinterpret_cast<const float4*>(x + (size_t)row * 1024)[t];
  float s = v.x + v.y + v.z + v.w;
  float q = v.x*v.x + v.y*v.y + v.z*v.z + v.w*v.w;
  #pragma unroll
  for (int off = 32; off >= 1; off >>= 1) {
    s += __shfl_xor(s, off);
    q += __shfl_xor(q, off);
  }
  __shared__ float ls[4], lq[4];
  const int wave = t >> 6, lane = t & 63;
  if (lane == 0) { ls[wave] = s; lq[wave] = q; }
  __syncthreads();
  s = ls[0] + ls[1] + ls[2] + ls[3];
  q = lq[0] + lq[1] + lq[2] + lq[3];
  const float mean = s * (1.0f/1024.0f);
  const float var  = q * (1.0f/1024.0f) - mean*mean;
  const float rstd = rsqrtf(var + 1e-6f);
  const float4 gm = reinterpret_cast<const float4*>(gamma)[t];
  const float4 bt = reinterpret_cast<const float4*>(beta)[t];
  ushort4 o;
  o.x = bf16_bits((v.x - mean)*rstd*gm.x + bt.x);
  o.y = bf16_bits((v.y - mean)*rstd*gm.y + bt.y);
  o.z = bf16_bits((v.z - mean)*rstd*gm.z + bt.z);
  o.w = bf16_bits((v.w - mean)*rstd*gm.w + bt.w);
  reinterpret_cast<ushort4*>(xn + (size_t)row*1024)[t] = o;
}

// ---------------- f32 -> bf16 convert (1M elements per launch) ----------------
__global__ __launch_bounds__(256) void cvt_kernel(const float* __restrict__ src,
                                                  __hip_bfloat16* __restrict__ dst)
{
  const int i = blockIdx.x * 256 + threadIdx.x;
  const float4 v = reinterpret_cast<const float4*>(src)[i];
  ushort4 o;
  o.x = bf16_bits(v.x); o.y = bf16_bits(v.y);
  o.z = bf16_bits(v.z); o.w = bf16_bits(v.w);
  reinterpret_cast<ushort4*>(dst)[i] = o;
}

// ---------------- NT-GEMM 256x256, BK=64, 8 waves, deep-pipelined ----------------
// C[M][N] = A[M][K]*B[N][K]^T, K=1024 (16 K-tiles).
// LDS 128KB: 2 buffers x (A[256][64] + B[256][64]) bf16, XOR-swizzled
// (byte ^= (row&7)<<4) via pre-swizzled GLOBAL source + linear LDS dest.
// Schedule per K-tile: compute(64 MFMA/wave) -> barrier -> stage tile+2 ->
// vmcnt(8) [tile+1 landed, tile+2 in flight] -> barrier. Never vmcnt(0) mid-loop.
template<int MODE>
__global__ __launch_bounds__(512, 2) void gemm256(
    const __hip_bfloat16* __restrict__ A,
    const __hip_bfloat16* __restrict__ B,
    const float* __restrict__ bias0,
    const float* __restrict__ bias1,
    void* __restrict__ C0,
    void* __restrict__ C1)
{
  constexpr int K = 1024;
  constexpr int NT = 16;  // K/64
  __shared__ __align__(16) __hip_bfloat16 Al[2][256*64];
  __shared__ __align__(16) __hip_bfloat16 Bl[2][256*64];
  const int t = threadIdx.x;
  const int wave = t >> 6, lane = t & 63;
  const int li = lane & 15, g = lane >> 4;
  const int wm = (wave >> 2) * 128;  // 2 M-groups of 128
  const int wn = (wave & 3) * 64;    // 4 N-groups of 64

  // XCD swizzle (gridDim.x is pow2; total blocks multiple of 8)
  const int lin = blockIdx.y * gridDim.x + blockIdx.x;
  const int cpx = (gridDim.x * gridDim.y) >> 3;
  const int wg  = (lin & 7) * cpx + (lin >> 3);
  const int bx  = wg & (gridDim.x - 1);
  const int by  = wg >> __builtin_ctz(gridDim.x);
  const int m0 = by * 256, n0 = bx * 256;

  // staging: thread covers rows srow + r*64 (r=0..3), 16B chunk (t&7), swizzled
  const int srow = t >> 3;
  const int scb_e = ((((t & 7) * 16) ^ ((srow & 7) << 4)) >> 1);
  const __hip_bfloat16* ga = A + (size_t)(m0 + srow) * K + scb_e;
  const __hip_bfloat16* gb = B + (size_t)(n0 + srow) * K + scb_e;

  auto stage = [&](int buf, int kt) {
    const int ko = kt * 64;
    #pragma unroll
    for (int r = 0; r < 4; ++r) {
      gload_lds16(ga + (size_t)(r*64)*K + ko, &Al[buf][r*4096 + t*8]);
      gload_lds16(gb + (size_t)(r*64)*K + ko, &Bl[buf][r*4096 + t*8]);
    }
  };

  // ds_read offsets (elements): row*64 + ((ks*64 + g*16) ^ ((li&7)<<4))/2
  const int swz = (li & 7) << 4;
  const int rd0 = (((g*16)      ^ swz) >> 1);
  const int rd1 = (((g*16 + 64) ^ swz) >> 1);

  f32x4 acc[8][4] = {};

  stage(0, 0);
  stage(1, 1);
  asm volatile("s_waitcnt vmcnt(8)" ::: "memory");  // tile 0 landed; tile 1 in flight
  __builtin_amdgcn_sched_barrier(0);
  __builtin_amdgcn_s_barrier();

  for (int it = 0; it < NT; ++it) {
    const __hip_bfloat16* Ab = Al[it & 1];
    const __hip_bfloat16* Bb = Bl[it & 1];
    bf16x8 b0[4], b1[4];
    #pragma unroll
    for (int ni = 0; ni < 4; ++ni) {
      b0[ni] = *reinterpret_cast<const bf16x8*>(&Bb[(wn + ni*16 + li)*64 + rd0]);
      b1[ni] = *reinterpret_cast<const bf16x8*>(&Bb[(wn + ni*16 + li)*64 + rd1]);
    }
    #pragma unroll
    for (int mi = 0; mi < 8; ++mi) {
      const bf16x8 a0 = *reinterpret_cast<const bf16x8*>(&Ab[(wm + mi*16 + li)*64 + rd0]);
      const bf16x8 a1 = *reinterpret_cast<const bf16x8*>(&Ab[(wm + mi*16 + li)*64 + rd1]);
      __builtin_amdgcn_s_setprio(1);
      #pragma unroll
      for (int ni = 0; ni < 4; ++ni) {
        acc[mi][ni] = __builtin_amdgcn_mfma_f32_16x16x32_bf16(a0, b0[ni], acc[mi][ni], 0, 0, 0);
        acc[mi][ni] = __builtin_amdgcn_mfma_f32_16x16x32_bf16(a1, b1[ni], acc[mi][ni], 0, 0, 0);
      }
      __builtin_amdgcn_s_setprio(0);
    }

    __builtin_amdgcn_s_barrier();  // all waves done reading buf[it&1]

    if (it + 2 < NT) {
      stage(it & 1, it + 2);                           // overwrite the buffer just read
      asm volatile("s_waitcnt vmcnt(8)" ::: "memory"); // tile it+1 landed; it+2 in flight
    } else {
      asm volatile("s_waitcnt vmcnt(0)" ::: "memory"); // tail drain
    }
    __builtin_amdgcn_sched_barrier(0);
    __builtin_amdgcn_s_barrier();                      // next tile visible to all waves
  }

  #pragma unroll
  for (int mi = 0; mi < 8; ++mi) {
    #pragma unroll
    for (int ni = 0; ni < 4; ++ni) {
      #pragma unroll
      for (int r = 0; r < 4; ++r) {
        const int grow = m0 + wm + mi*16 + g*4 + r;
        const int gcol = n0 + wn + ni*16 + li;
        float v = acc[mi][ni][r];
        if constexpr (MODE == 0) {
          const int b = grow >> 11, ss = grow & 2047;
          if (gcol < 1024) {
            // fold 1/sqrt(hd) AND log2(e) into Q so attn uses exp2 directly
            v = (v + bias0[gcol]) * (0.125f * LOG2E);
            const int h = gcol >> 6, d = gcol & 63;
            ((__hip_bfloat16*)C0)[(((size_t)(b*16 + h))*2048 + ss)*64 + d] = __float2bfloat16(v);
          } else {
            const int c2 = gcol - 1024;
            v = v + bias1[c2];
            const int h = c2 >> 6, d = c2 & 63;
            ((__hip_bfloat16*)C1)[(((size_t)(b*16 + h))*2048 + ss)*64 + d] = __float2bfloat16(v);
          }
        } else if constexpr (MODE == 1) {
          v += bias0[grow];
          ((__hip_bfloat16*)C0)[(size_t)grow*8192 + gcol] = __float2bfloat16(v);
        } else {
          v += bias0[gcol];
          ((float*)C0)[(size_t)grow*1024 + gcol] = v;
        }
      }
    }
  }
}

// ---------------- Flash attention (in-register P: cvt_pk + permlane swaps) -------
// grid 1024 blocks x 256 threads = 4 waves; wave owns 32 q-rows (2 x 16-row subtiles).
// Q: [bh][s][64] bf16 pre-scaled by 0.125*log2(e). K: [bh][s][64]. Vt: [1024][8192].
// Zero-max softmax (scores bounded; |s| << exp2 overflow).
// P never touches LDS (cvt_pk + permlane32/16_swap redistribution).
// LDS = 32 KB (K/V dbuf only). SQ_LDS_BANK_CONFLICT = 0 (R8 measured).
__global__ __launch_bounds__(256, 4) void attn_kernel(
    const __hip_bfloat16* __restrict__ Q,
    const __hip_bfloat16* __restrict__ K,
    const __hip_bfloat16* __restrict__ Vt,
    __hip_bfloat16* __restrict__ ctx)
{
  const int t = threadIdx.x, wave = t >> 6, lane = t & 63;
  const int li = lane & 15, g = lane >> 4;

  // XCD-chunked decode: 1024 blocks, 128 per XCD = 8 bh per XCD
  const int lin = blockIdx.x;
  const int wg  = (lin & 7) * 128 + (lin >> 3);
  const int bh  = wg >> 4, qt = wg & 15;
  const int b = bh >> 4, h = bh & 15;
  const int qbase = qt * 128 + wave * 32;

  __shared__ __align__(16) __hip_bfloat16 Klds[2][4096];  // 16 KB
  __shared__ __align__(16) __hip_bfloat16 Vlds[2][4096];  // 16 KB

  const bf16x8* Qv0 = reinterpret_cast<const bf16x8*>(Q + ((size_t)bh*2048 + qbase + li)*64 + g*8);
  const bf16x8* Qv1 = reinterpret_cast<const bf16x8*>(Q + ((size_t)bh*2048 + qbase + 16 + li)*64 + g*8);
  const bf16x8 aQ00 = Qv0[0], aQ01 = Qv0[4];
  const bf16x8 aQ10 = Qv1[0], aQ11 = Qv1[4];

  f32x4 acc0[4] = {}, acc1[4] = {};
  float l0 = 0.f, l1 = 0.f;   // per-lane partial sums (q = li of each subtile)

  const __hip_bfloat16* Kbh = K + (size_t)bh*2048*64;
  const __hip_bfloat16* Vbh = Vt + (size_t)h*64*8192 + b*2048;

  // staging: 256 threads x 2 chunks cover 64 rows x 128B; swizzle byte ^= (row&7)<<4
  // pre-applied on the GLOBAL source (linear LDS dest, rule #21)
  const int l8 = lane >> 3;
  const int scb_e = ((((lane & 7) * 16) ^ (l8 << 4)) >> 1);  // elements
  const int row0 = wave * 8 + l8;

  // ds_read offsets (elements), swizzle applied on read
  const int krd0 = (li*128 + ((g*16)      ^ ((li & 7) << 4))) >> 1;
  const int krd1 = (li*128 + ((g*16 + 64) ^ ((li & 7) << 4))) >> 1;

  // prologue: stage tile 0 into buffer 0
  gload_lds16(Kbh + (size_t)row0*64 + scb_e,        &Klds[0][wave*512]);
  gload_lds16(Kbh + (size_t)(32+row0)*64 + scb_e,   &Klds[0][2048 + wave*512]);
  gload_lds16(Vbh + (size_t)row0*8192 + scb_e,      &Vlds[0][wave*512]);
  gload_lds16(Vbh + (size_t)(32+row0)*8192 + scb_e, &Vlds[0][2048 + wave*512]);
  __syncthreads();

  const __hip_bfloat16* kSrc = Kbh + (size_t)(64 + row0)*64 + scb_e;
  const __hip_bfloat16* vSrc = Vbh + (size_t)row0*8192 + 64 + scb_e;

  int cur = 0;
  for (int it = 0; it < 32; ++it) {
    if (it < 31) {
      __hip_bfloat16* kD = Klds[cur^1];
      __hip_bfloat16* vD = Vlds[cur^1];
      gload_lds16(kSrc,           kD + wave*512);
      gload_lds16(kSrc + 32*64,   kD + 2048 + wave*512);
      gload_lds16(vSrc,           vD + wave*512);
      gload_lds16(vSrc + 32*8192, vD + 2048 + wave*512);
      kSrc += 64*64;
      vSrc += 64;
    }

    const __hip_bfloat16* Kc = Klds[cur];
    const __hip_bfloat16* Vc = Vlds[cur];

    // QK^T swapped, both subtiles per K-frag read:
    // s_u[nt] holds S[k=nt*16+g*4+r][q=li] for subtile u
    f32x4 s0[4] = {}, s1[4] = {};
    __builtin_amdgcn_s_setprio(1);
    #pragma unroll
    for (int nt = 0; nt < 4; ++nt) {
      const bf16x8 k0 = *reinterpret_cast<const bf16x8*>(&Kc[nt*1024 + krd0]);
      const bf16x8 k1 = *reinterpret_cast<const bf16x8*>(&Kc[nt*1024 + krd1]);
      s0[nt] = __builtin_amdgcn_mfma_f32_16x16x32_bf16(k0, aQ00, s0[nt], 0, 0, 0);
      s0[nt] = __builtin_amdgcn_mfma_f32_16x16x32_bf16(k1, aQ01, s0[nt], 0, 0, 0);
      s1[nt] = __builtin_amdgcn_mfma_f32_16x16x32_bf16(k0, aQ10, s1[nt], 0, 0, 0);
      s1[nt] = __builtin_amdgcn_mfma_f32_16x16x32_bf16(k1, aQ11, s1[nt], 0, 0, 0);
    }
    __builtin_amdgcn_s_setprio(0);

    // zero-max softmax: p = exp2(s); per-lane partial l
    float sm0 = 0.f, sm1 = 0.f;
    #pragma unroll
    for (int nt = 0; nt < 4; ++nt)
      #pragma unroll
      for (int r = 0; r < 4; ++r) {
        const float p0 = exp2f(s0[nt][r]); s0[nt][r] = p0; sm0 += p0;
        const float p1 = exp2f(s1[nt][r]); s1[nt][r] = p1; sm1 += p1;
      }
    l0 += sm0; l1 += sm1;

    // ---- in-register P redistribution (per subtile):
    // c[nt][w] = bf16 pair for k = nt*16 + g*4 + 2w.
    // banks (0,1) -> aP_lo (k = g*8+j), banks (2,3) -> aP_hi (k = 32+g*8+j)
    union U8 { uint32_t w[4]; bf16x8 v; };
    bf16x8 aP00, aP01, aP10, aP11;
    {
      uint32_t c[4][2];
      #pragma unroll
      for (int nt = 0; nt < 4; ++nt) {
        c[nt][0] = cvtpk_bf16(s0[nt][0], s0[nt][1]);
        c[nt][1] = cvtpk_bf16(s0[nt][2], s0[nt][3]);
      }
      uint32_t x0 = c[0][0], y0 = c[1][0], x1 = c[0][1], y1 = c[1][1];
      plswap32(x0, y0); plswap32(x1, y1);
      plswap16(x0, y0); plswap16(x1, y1);
      U8 u0; u0.w[0] = x0; u0.w[1] = x1; u0.w[2] = y0; u0.w[3] = y1;
      aP00 = u0.v;
      uint32_t x2 = c[2][0], y2 = c[3][0], x3 = c[2][1], y3 = c[3][1];
      plswap32(x2, y2); plswap32(x3, y3);
      plswap16(x2, y2); plswap16(x3, y3);
      U8 u1; u1.w[0] = x2; u1.w[1] = x3; u1.w[2] = y2; u1.w[3] = y3;
      aP01 = u1.v;
    }
    {
      uint32_t c[4][2];
      #pragma unroll
      for (int nt = 0; nt < 4; ++nt) {
        c[nt][0] = cvtpk_bf16(s1[nt][0], s1[nt][1]);
        c[nt][1] = cvtpk_bf16(s1[nt][2], s1[nt][3]);
      }
      uint32_t x0 = c[0][0], y0 = c[1][0], x1 = c[0][1], y1 = c[1][1];
      plswap32(x0, y0); plswap32(x1, y1);
      plswap16(x0, y0); plswap16(x1, y1);
      U8 u0; u0.w[0] = x0; u0.w[1] = x1; u0.w[2] = y0; u0.w[3] = y1;
      aP10 = u0.v;
      uint32_t x2 = c[2][0], y2 = c[3][0], x3 = c[2][1], y3 = c[3][1];
      plswap32(x2, y2); plswap32(x3, y3);
      plswap16(x2, y2); plswap16(x3, y3);
      U8 u1; u1.w[0] = x2; u1.w[1] = x3; u1.w[2] = y2; u1.w[3] = y3;
      aP11 = u1.v;
    }

    // PV swapped, both subtiles per V-frag read
    __builtin_amdgcn_s_setprio(1);
    #pragma unroll
    for (int dt = 0; dt < 4; ++dt) {
      const bf16x8 v0 = *reinterpret_cast<const bf16x8*>(&Vc[dt*1024 + krd0]);
      const bf16x8 v1 = *reinterpret_cast<const bf16x8*>(&Vc[dt*1024 + krd1]);
      acc0[dt] = __builtin_amdgcn_mfma_f32_16x16x32_bf16(v0, aP00, acc0[dt], 0, 0, 0);
      acc0[dt] = __builtin_amdgcn_mfma_f32_16x16x32_bf16(v1, aP01, acc0[dt], 0, 0, 0);
      acc1[dt] = __builtin_amdgcn_mfma_f32_16x16x32_bf16(v0, aP10, acc1[dt], 0, 0, 0);
      acc1[dt] = __builtin_amdgcn_mfma_f32_16x16x32_bf16(v1, aP11, acc1[dt], 0, 0, 0);
    }
    __builtin_amdgcn_s_setprio(0);

    // barrier drains vmcnt (staged tile complete) + syncs buffer reuse
    __syncthreads();
    cur ^= 1;
  }

  // reduce l across the 4 g-groups (same q=li)
  l0 += __shfl_xor(l0, 16); l0 += __shfl_xor(l0, 32);
  l1 += __shfl_xor(l1, 16); l1 += __shfl_xor(l1, 32);
  const float inv0 = 1.0f / l0;
  const float inv1 = 1.0f / l1;

  __hip_bfloat16* cp = ctx + ((size_t)(b*2048 + qbase))*1024 + h*64;
  #pragma unroll
  for (int dt = 0; dt < 4; ++dt) {
    ushort4 o0, o1;
    o0.x = bf16_bits(acc0[dt][0] * inv0);
    o0.y = bf16_bits(acc0[dt][1] * inv0);
    o0.z = bf16_bits(acc0[dt][2] * inv0);
    o0.w = bf16_bits(acc0[dt][3] * inv0);
    *reinterpret_cast<ushort4*>(&cp[(size_t)li*1024 + dt*16 + g*4]) = o0;
    o1.x = bf16_bits(acc1[dt][0] * inv1);
    o1.y = bf16_bits(acc1[dt][1] * inv1);
    o1.z = bf16_bits(acc1[dt][2] * inv1);
    o1.w = bf16_bits(acc1[dt][3] * inv1);
    *reinterpret_cast<ushort4*>(&cp[(size_t)(16 + li)*1024 + dt*16 + g*4]) = o1;
  }
}

extern "C" void kernel_launch(void* const* d_in, const int* in_sizes, int n_in,
                              void* d_out, int out_size, void* d_ws, size_t ws_size,
                              hipStream_t stream)
{
  const float* x  = (const float*)d_in[0];
  const float* g  = (const float*)d_in[1];
  const float* be = (const float*)d_in[2];
  const float* Wq = (const float*)d_in[3];
  const float* bq = (const float*)d_in[4];
  const float* Wk = (const float*)d_in[5];
  const float* bk = (const float*)d_in[6];
  const float* Wv = (const float*)d_in[7];
  const float* bv = (const float*)d_in[8];
  const float* Wo = (const float*)d_in[9];
  const float* bo = (const float*)d_in[10];
  float* out = (float*)d_out;

  char* ws = (char*)d_ws;
  __hip_bfloat16* xn  = (__hip_bfloat16*)(ws);              // 16 MB
  __hip_bfloat16* Wqk = (__hip_bfloat16*)(ws + 16777216);   // 4 MB  [2048][1024]
  __hip_bfloat16* Wvb = (__hip_bfloat16*)(ws + 20971520);   // 2 MB
  __hip_bfloat16* Wob = (__hip_bfloat16*)(ws + 23068672);   // 2 MB
  __hip_bfloat16* Qb  = (__hip_bfloat16*)(ws + 25165824);   // 16 MB [bh][s][64]
  __hip_bfloat16* Kb  = (__hip_bfloat16*)(ws + 41943040);   // 16 MB
  __hip_bfloat16* Vt  = (__hip_bfloat16*)(ws + 58720256);   // 16 MB [1024][8192]
  __hip_bfloat16* ctx = (__hip_bfloat16*)(ws + 75497472);   // 16 MB [8192][1024]

  ln_kernel<<<8192, 256, 0, stream>>>(x, g, be, xn);
  cvt_kernel<<<1024, 256, 0, stream>>>(Wq, Wqk);
  cvt_kernel<<<1024, 256, 0, stream>>>(Wk, Wqk + 1024*1024);
  cvt_kernel<<<1024, 256, 0, stream>>>(Wv, Wvb);
  cvt_kernel<<<1024, 256, 0, stream>>>(Wo, Wob);

  // Q,K projections: [8192 x 2048] = xn @ [Wq;Wk]^T  (256 blocks = 1/CU)
  gemm256<0><<<dim3(8, 32), 512, 0, stream>>>(xn, Wqk, bq, bk, Qb, Kb);
  // V^T: [1024 x 8192] = Wv @ xn^T  (NT with A=Wv, B=xn)
  gemm256<1><<<dim3(32, 4), 512, 0, stream>>>(Wvb, xn, bv, nullptr, Vt, nullptr);
  // attention: 1024 blocks x 256 threads (4 waves x 32 q-rows)
  attn_kernel<<<1024, 256, 0, stream>>>(Qb, Kb, Vt, ctx);
  // output projection: [8192 x 1024] = ctx @ Wo^T + bo (f32 out)
  gemm256<2><<<dim3(4, 32), 512, 0, stream>>>(ctx, Wob, bo, nullptr, out, nullptr);
}

// Round 11
// 225.342 us; speedup vs baseline: 1.1460x; 1.1369x over previous
//
#include <hip/hip_runtime.h>
#include <hip/hip_bf16.h>
#include <stdint.h>

typedef __bf16 bf16x8 __attribute__((ext_vector_type(8)));
typedef float f32x4 __attribute__((ext_vector_type(4)));

#define LOG2E 1.44269504088896340736f

__device__ inline void gload_lds16(const void* g, void* l) {
  __builtin_amdgcn_global_load_lds((const __attribute__((address_space(1))) void*)g,
                                   (__attribute__((address_space(3))) void*)l, 16, 0, 0);
}

__device__ inline unsigned short bf16_bits(float f) {
  return __builtin_bit_cast(unsigned short, __float2bfloat16(f));
}

// pack two f32 -> one u32 of 2 bf16 (low = first arg)
__device__ inline uint32_t cvtpk_bf16(float lo, float hi) {
  uint32_t d;
  asm("v_cvt_pk_bf16_f32 %0, %1, %2" : "=v"(d) : "v"(lo), "v"(hi));
  return d;
}
// gfx950 cross-lane row swaps
__device__ inline void plswap32(uint32_t& a, uint32_t& b) {
  asm("v_permlane32_swap_b32 %0, %1" : "+v"(a), "+v"(b));
}
__device__ inline void plswap16(uint32_t& a, uint32_t& b) {
  asm("v_permlane16_swap_b32 %0, %1" : "+v"(a), "+v"(b));
}

// ---------------- prep: LN (blocks 0..8191) + weight cvt (blocks 8192..12287) ----
__global__ __launch_bounds__(256) void prep_kernel(
    const float* __restrict__ x, const float* __restrict__ gamma,
    const float* __restrict__ beta, __hip_bfloat16* __restrict__ xn,
    const float* __restrict__ Wq, const float* __restrict__ Wk,
    const float* __restrict__ Wv, const float* __restrict__ Wo,
    __hip_bfloat16* __restrict__ Wqk, __hip_bfloat16* __restrict__ Wvb,
    __hip_bfloat16* __restrict__ Wob)
{
  const int t = threadIdx.x;
  if (blockIdx.x < 8192) {
    const int row = blockIdx.x;
    const float4 v = reinterpret_cast<const float4*>(x + (size_t)row * 1024)[t];
    float s = v.x + v.y + v.z + v.w;
    float q = v.x*v.x + v.y*v.y + v.z*v.z + v.w*v.w;
    #pragma unroll
    for (int off = 32; off >= 1; off >>= 1) {
      s += __shfl_xor(s, off);
      q += __shfl_xor(q, off);
    }
    __shared__ float ls[4], lq[4];
    const int wave = t >> 6, lane = t & 63;
    if (lane == 0) { ls[wave] = s; lq[wave] = q; }
    __syncthreads();
    s = ls[0] + ls[1] + ls[2] + ls[3];
    q = lq[0] + lq[1] + lq[2] + lq[3];
    const float mean = s * (1.0f/1024.0f);
    const float var  = q * (1.0f/1024.0f) - mean*mean;
    const float rstd = rsqrtf(var + 1e-6f);
    const float4 gm = reinterpret_cast<const float4*>(gamma)[t];
    const float4 bt = reinterpret_cast<const float4*>(beta)[t];
    ushort4 o;
    o.x = bf16_bits((v.x - mean)*rstd*gm.x + bt.x);
    o.y = bf16_bits((v.y - mean)*rstd*gm.y + bt.y);
    o.z = bf16_bits((v.z - mean)*rstd*gm.z + bt.z);
    o.w = bf16_bits((v.w - mean)*rstd*gm.w + bt.w);
    reinterpret_cast<ushort4*>(xn + (size_t)row*1024)[t] = o;
  } else {
    const int cb = blockIdx.x - 8192;        // 0..4095
    const int which = cb >> 10;              // 0..3
    const int i = (cb & 1023) * 256 + t;     // 0..1M-1
    const float* src;
    __hip_bfloat16* dst;
    if (which == 0)      { src = Wq; dst = Wqk; }
    else if (which == 1) { src = Wk; dst = Wqk + 1024*1024; }
    else if (which == 2) { src = Wv; dst = Wvb; }
    else                 { src = Wo; dst = Wob; }
    const float4 v = reinterpret_cast<const float4*>(src)[i];
    ushort4 o;
    o.x = bf16_bits(v.x); o.y = bf16_bits(v.y);
    o.z = bf16_bits(v.z); o.w = bf16_bits(v.w);
    reinterpret_cast<ushort4*>(dst)[i] = o;
  }
}

// ---------------- merged QKV NT-GEMM (gemm0: Q,K; gemm1: Vt) -------------------
// 1536 blocks: wg<1024 -> C=[Q;K] tiles (16x64); wg>=1024 -> Vt tiles (64x8).
// 128x128 tile, 4 waves, BK=32, K=1024, m97 structure (R8-proven).
__global__ __launch_bounds__(256) void qkv_gemm(
    const __hip_bfloat16* __restrict__ xn,
    const __hip_bfloat16* __restrict__ Wqk,
    const __hip_bfloat16* __restrict__ Wvb,
    const float* __restrict__ bq, const float* __restrict__ bk,
    const float* __restrict__ bv,
    __hip_bfloat16* __restrict__ Qb, __hip_bfloat16* __restrict__ Kb,
    __hip_bfloat16* __restrict__ Vt)
{
  constexpr int K = 1024;
  __shared__ __align__(16) __hip_bfloat16 Al[128*32];
  __shared__ __align__(16) __hip_bfloat16 Bl[128*32];
  const int t = threadIdx.x;
  const int wave = t >> 6, lane = t & 63;
  const int li = lane & 15, g = lane >> 4;
  const int wm = (wave >> 1) * 64, wn = (wave & 1) * 64;

  // XCD-bijective swizzle over 1536 blocks (192 per XCD)
  const int lin = blockIdx.x;
  const int wg  = (lin & 7) * 192 + (lin >> 3);
  const bool isV = wg >= 1024;
  int m0, n0;
  const __hip_bfloat16 *A, *B;
  if (!isV) {
    m0 = (wg >> 4) * 128; n0 = (wg & 15) * 128;   // A-panel shared across 16
    A = xn; B = Wqk;
  } else {
    const int w2 = wg - 1024;
    m0 = (w2 & 7) * 128; n0 = (w2 >> 3) * 128;    // B-panel shared across 8
    A = Wvb; B = xn;
  }
  const int srow = t >> 2, sch = (t & 3) * 8;

  const __hip_bfloat16* ga = A + (size_t)(m0 + srow) * K + sch;
  const __hip_bfloat16* gb = B + (size_t)(n0 + srow) * K + sch;

  f32x4 acc[4][4] = {};

  for (int kt = 0; kt < K; kt += 32) {
    gload_lds16(ga + kt,          Al + t*8);
    gload_lds16(ga + kt + 64*K,   Al + t*8 + 2048);
    gload_lds16(gb + kt,          Bl + t*8);
    gload_lds16(gb + kt + 64*K,   Bl + t*8 + 2048);
    __syncthreads();
    bf16x8 af[4], bfr[4];
    #pragma unroll
    for (int mi = 0; mi < 4; ++mi)
      af[mi] = *reinterpret_cast<const bf16x8*>(Al + (wm + mi*16 + li)*32 + g*8);
    #pragma unroll
    for (int ni = 0; ni < 4; ++ni)
      bfr[ni] = *reinterpret_cast<const bf16x8*>(Bl + (wn + ni*16 + li)*32 + g*8);
    #pragma unroll
    for (int mi = 0; mi < 4; ++mi)
      #pragma unroll
      for (int ni = 0; ni < 4; ++ni)
        acc[mi][ni] = __builtin_amdgcn_mfma_f32_16x16x32_bf16(af[mi], bfr[ni], acc[mi][ni], 0, 0, 0);
    __syncthreads();
  }

  #pragma unroll
  for (int mi = 0; mi < 4; ++mi) {
    #pragma unroll
    for (int ni = 0; ni < 4; ++ni) {
      #pragma unroll
      for (int r = 0; r < 4; ++r) {
        const int grow = m0 + wm + mi*16 + g*4 + r;
        const int gcol = n0 + wn + ni*16 + li;
        float v = acc[mi][ni][r];
        if (!isV) {
          const int b = grow >> 11, ss = grow & 2047;
          if (gcol < 1024) {
            // fold 1/sqrt(hd) AND log2(e) into Q so attn uses exp2 directly
            v = (v + bq[gcol]) * (0.125f * LOG2E);
            const int h = gcol >> 6, d = gcol & 63;
            Qb[(((size_t)(b*16 + h))*2048 + ss)*64 + d] = __float2bfloat16(v);
          } else {
            const int c2 = gcol - 1024;
            v = v + bk[c2];
            const int h = c2 >> 6, d = c2 & 63;
            Kb[(((size_t)(b*16 + h))*2048 + ss)*64 + d] = __float2bfloat16(v);
          }
        } else {
          v += bv[grow];
          Vt[(size_t)grow*8192 + gcol] = __float2bfloat16(v);
        }
      }
    }
  }
}

// ---------------- output projection NT-GEMM (R8-proven 128x128) ----------------
__global__ __launch_bounds__(256) void out_gemm(
    const __hip_bfloat16* __restrict__ A,
    const __hip_bfloat16* __restrict__ B,
    const float* __restrict__ bias,
    float* __restrict__ C)
{
  constexpr int K = 1024;
  __shared__ __align__(16) __hip_bfloat16 Al[128*32];
  __shared__ __align__(16) __hip_bfloat16 Bl[128*32];
  const int t = threadIdx.x;
  const int wave = t >> 6, lane = t & 63;
  const int li = lane & 15, g = lane >> 4;
  const int wm = (wave >> 1) * 64, wn = (wave & 1) * 64;

  const int lin = blockIdx.y * gridDim.x + blockIdx.x;
  const int cpx = (gridDim.x * gridDim.y) >> 3;
  const int wg  = (lin & 7) * cpx + (lin >> 3);
  const int bx  = wg & (gridDim.x - 1);
  const int by  = wg >> __builtin_ctz(gridDim.x);
  const int m0 = by * 128, n0 = bx * 128;
  const int srow = t >> 2, sch = (t & 3) * 8;

  const __hip_bfloat16* ga = A + (size_t)(m0 + srow) * K + sch;
  const __hip_bfloat16* gb = B + (size_t)(n0 + srow) * K + sch;

  f32x4 acc[4][4] = {};

  for (int kt = 0; kt < K; kt += 32) {
    gload_lds16(ga + kt,          Al + t*8);
    gload_lds16(ga + kt + 64*K,   Al + t*8 + 2048);
    gload_lds16(gb + kt,          Bl + t*8);
    gload_lds16(gb + kt + 64*K,   Bl + t*8 + 2048);
    __syncthreads();
    bf16x8 af[4], bfr[4];
    #pragma unroll
    for (int mi = 0; mi < 4; ++mi)
      af[mi] = *reinterpret_cast<const bf16x8*>(Al + (wm + mi*16 + li)*32 + g*8);
    #pragma unroll
    for (int ni = 0; ni < 4; ++ni)
      bfr[ni] = *reinterpret_cast<const bf16x8*>(Bl + (wn + ni*16 + li)*32 + g*8);
    #pragma unroll
    for (int mi = 0; mi < 4; ++mi)
      #pragma unroll
      for (int ni = 0; ni < 4; ++ni)
        acc[mi][ni] = __builtin_amdgcn_mfma_f32_16x16x32_bf16(af[mi], bfr[ni], acc[mi][ni], 0, 0, 0);
    __syncthreads();
  }

  #pragma unroll
  for (int mi = 0; mi < 4; ++mi) {
    #pragma unroll
    for (int ni = 0; ni < 4; ++ni) {
      #pragma unroll
      for (int r = 0; r < 4; ++r) {
        const int grow = m0 + wm + mi*16 + g*4 + r;
        const int gcol = n0 + wn + ni*16 + li;
        C[(size_t)grow*1024 + gcol] = acc[mi][ni][r] + bias[gcol];
      }
    }
  }
}

// ---------------- Flash attention (counted-vmcnt pipeline, in-register P) -------
// grid 1024 x 256 threads = 4 waves; wave owns 32 q-rows (2 x 16-row subtiles).
// Q pre-scaled by 0.125*log2(e); zero-max softmax p=exp2(s).
// T4 schedule: raw s_barrier for WAR sync, stage tile i+2, vmcnt(4) waits ONLY
// tile i+1 (issued a full iteration earlier -> landed), second s_barrier.
// Never vmcnt(0) mid-loop. LDS = 32 KB -> 4 blocks/CU, grid = exactly 4x256 CU.
__global__ __launch_bounds__(256, 4) void attn_kernel(
    const __hip_bfloat16* __restrict__ Q,
    const __hip_bfloat16* __restrict__ K,
    const __hip_bfloat16* __restrict__ Vt,
    __hip_bfloat16* __restrict__ ctx)
{
  const int t = threadIdx.x, wave = t >> 6, lane = t & 63;
  const int li = lane & 15, g = lane >> 4;

  // XCD-chunked decode: 1024 blocks, 128 per XCD = 8 bh per XCD
  const int lin = blockIdx.x;
  const int wg  = (lin & 7) * 128 + (lin >> 3);
  const int bh  = wg >> 4, qt = wg & 15;
  const int b = bh >> 4, h = bh & 15;
  const int qbase = qt * 128 + wave * 32;

  __shared__ __align__(16) __hip_bfloat16 Klds[2][4096];  // 16 KB
  __shared__ __align__(16) __hip_bfloat16 Vlds[2][4096];  // 16 KB

  const bf16x8* Qv0 = reinterpret_cast<const bf16x8*>(Q + ((size_t)bh*2048 + qbase + li)*64 + g*8);
  const bf16x8* Qv1 = reinterpret_cast<const bf16x8*>(Q + ((size_t)bh*2048 + qbase + 16 + li)*64 + g*8);
  const bf16x8 aQ00 = Qv0[0], aQ01 = Qv0[4];
  const bf16x8 aQ10 = Qv1[0], aQ11 = Qv1[4];

  f32x4 acc0[4] = {}, acc1[4] = {};
  float l0 = 0.f, l1 = 0.f;

  const __hip_bfloat16* Kbh = K + (size_t)bh*2048*64;
  const __hip_bfloat16* Vbh = Vt + (size_t)h*64*8192 + b*2048;

  // staging geometry: swizzle byte ^= (row&7)<<4 pre-applied on GLOBAL source
  const int l8 = lane >> 3;
  const int scb_e = ((((lane & 7) * 16) ^ (l8 << 4)) >> 1);
  const int row0 = wave * 8 + l8;

  // ds_read offsets, swizzle applied on read
  const int krd0 = (li*128 + ((g*16)      ^ ((li & 7) << 4))) >> 1;
  const int krd1 = (li*128 + ((g*16 + 64) ^ ((li & 7) << 4))) >> 1;

  // prologue: stage tiles 0 and 1 (8 loads in flight/wave)
  gload_lds16(Kbh + (size_t)row0*64 + scb_e,          &Klds[0][wave*512]);
  gload_lds16(Kbh + (size_t)(32+row0)*64 + scb_e,     &Klds[0][2048 + wave*512]);
  gload_lds16(Vbh + (size_t)row0*8192 + scb_e,        &Vlds[0][wave*512]);
  gload_lds16(Vbh + (size_t)(32+row0)*8192 + scb_e,   &Vlds[0][2048 + wave*512]);
  gload_lds16(Kbh + (size_t)(64+row0)*64 + scb_e,     &Klds[1][wave*512]);
  gload_lds16(Kbh + (size_t)(96+row0)*64 + scb_e,     &Klds[1][2048 + wave*512]);
  gload_lds16(Vbh + (size_t)row0*8192 + 64 + scb_e,   &Vlds[1][wave*512]);
  gload_lds16(Vbh + (size_t)(32+row0)*8192 + 64 + scb_e, &Vlds[1][2048 + wave*512]);
  asm volatile("s_waitcnt vmcnt(4)" ::: "memory");  // tile 0 landed; tile 1 in flight
  __builtin_amdgcn_sched_barrier(0);
  __builtin_amdgcn_s_barrier();

  // loop staging starts at tile 2
  const __hip_bfloat16* kSrc = Kbh + (size_t)(128 + row0)*64 + scb_e;
  const __hip_bfloat16* vSrc = Vbh + (size_t)row0*8192 + 128 + scb_e;

  for (int it = 0; it < 32; ++it) {
    const int cur = it & 1;
    const __hip_bfloat16* Kc = Klds[cur];
    const __hip_bfloat16* Vc = Vlds[cur];

    // QK^T swapped, both subtiles per K-frag read
    f32x4 s0[4] = {}, s1[4] = {};
    __builtin_amdgcn_s_setprio(1);
    #pragma unroll
    for (int nt = 0; nt < 4; ++nt) {
      const bf16x8 k0 = *reinterpret_cast<const bf16x8*>(&Kc[nt*1024 + krd0]);
      const bf16x8 k1 = *reinterpret_cast<const bf16x8*>(&Kc[nt*1024 + krd1]);
      s0[nt] = __builtin_amdgcn_mfma_f32_16x16x32_bf16(k0, aQ00, s0[nt], 0, 0, 0);
      s0[nt] = __builtin_amdgcn_mfma_f32_16x16x32_bf16(k1, aQ01, s0[nt], 0, 0, 0);
      s1[nt] = __builtin_amdgcn_mfma_f32_16x16x32_bf16(k0, aQ10, s1[nt], 0, 0, 0);
      s1[nt] = __builtin_amdgcn_mfma_f32_16x16x32_bf16(k1, aQ11, s1[nt], 0, 0, 0);
    }
    __builtin_amdgcn_s_setprio(0);

    // zero-max softmax: p = exp2(s); per-lane partial l
    float sm0 = 0.f, sm1 = 0.f;
    #pragma unroll
    for (int nt = 0; nt < 4; ++nt)
      #pragma unroll
      for (int r = 0; r < 4; ++r) {
        const float p0 = exp2f(s0[nt][r]); s0[nt][r] = p0; sm0 += p0;
        const float p1 = exp2f(s1[nt][r]); s1[nt][r] = p1; sm1 += p1;
      }
    l0 += sm0; l1 += sm1;

    // in-register P redistribution (cvt_pk + permlane swaps)
    union U8 { uint32_t w[4]; bf16x8 v; };
    bf16x8 aP00, aP01, aP10, aP11;
    {
      uint32_t c[4][2];
      #pragma unroll
      for (int nt = 0; nt < 4; ++nt) {
        c[nt][0] = cvtpk_bf16(s0[nt][0], s0[nt][1]);
        c[nt][1] = cvtpk_bf16(s0[nt][2], s0[nt][3]);
      }
      uint32_t x0 = c[0][0], y0 = c[1][0], x1 = c[0][1], y1 = c[1][1];
      plswap32(x0, y0); plswap32(x1, y1);
      plswap16(x0, y0); plswap16(x1, y1);
      U8 u0; u0.w[0] = x0; u0.w[1] = x1; u0.w[2] = y0; u0.w[3] = y1;
      aP00 = u0.v;
      uint32_t x2 = c[2][0], y2 = c[3][0], x3 = c[2][1], y3 = c[3][1];
      plswap32(x2, y2); plswap32(x3, y3);
      plswap16(x2, y2); plswap16(x3, y3);
      U8 u1; u1.w[0] = x2; u1.w[1] = x3; u1.w[2] = y2; u1.w[3] = y3;
      aP01 = u1.v;
    }
    {
      uint32_t c[4][2];
      #pragma unroll
      for (int nt = 0; nt < 4; ++nt) {
        c[nt][0] = cvtpk_bf16(s1[nt][0], s1[nt][1]);
        c[nt][1] = cvtpk_bf16(s1[nt][2], s1[nt][3]);
      }
      uint32_t x0 = c[0][0], y0 = c[1][0], x1 = c[0][1], y1 = c[1][1];
      plswap32(x0, y0); plswap32(x1, y1);
      plswap16(x0, y0); plswap16(x1, y1);
      U8 u0; u0.w[0] = x0; u0.w[1] = x1; u0.w[2] = y0; u0.w[3] = y1;
      aP10 = u0.v;
      uint32_t x2 = c[2][0], y2 = c[3][0], x3 = c[2][1], y3 = c[3][1];
      plswap32(x2, y2); plswap32(x3, y3);
      plswap16(x2, y2); plswap16(x3, y3);
      U8 u1; u1.w[0] = x2; u1.w[1] = x3; u1.w[2] = y2; u1.w[3] = y3;
      aP11 = u1.v;
    }

    // PV swapped, both subtiles per V-frag read
    __builtin_amdgcn_s_setprio(1);
    #pragma unroll
    for (int dt = 0; dt < 4; ++dt) {
      const bf16x8 v0 = *reinterpret_cast<const bf16x8*>(&Vc[dt*1024 + krd0]);
      const bf16x8 v1 = *reinterpret_cast<const bf16x8*>(&Vc[dt*1024 + krd1]);
      acc0[dt] = __builtin_amdgcn_mfma_f32_16x16x32_bf16(v0, aP00, acc0[dt], 0, 0, 0);
      acc0[dt] = __builtin_amdgcn_mfma_f32_16x16x32_bf16(v1, aP01, acc0[dt], 0, 0, 0);
      acc1[dt] = __builtin_amdgcn_mfma_f32_16x16x32_bf16(v0, aP10, acc1[dt], 0, 0, 0);
      acc1[dt] = __builtin_amdgcn_mfma_f32_16x16x32_bf16(v1, aP11, acc1[dt], 0, 0, 0);
    }
    __builtin_amdgcn_s_setprio(0);

    if (it < 31) {
      // all waves done READING buf[cur] (V reads consumed by MFMAs above)
      __builtin_amdgcn_s_barrier();
      if (it < 30) {
        // stage tile it+2 into buf[cur]; then wait ONLY tile it+1 (oldest 4)
        gload_lds16(kSrc,           &Klds[cur][wave*512]);
        gload_lds16(kSrc + 32*64,   &Klds[cur][2048 + wave*512]);
        gload_lds16(vSrc,           &Vlds[cur][wave*512]);
        gload_lds16(vSrc + 32*8192, &Vlds[cur][2048 + wave*512]);
        kSrc += 64*64;
        vSrc += 64;
        asm volatile("s_waitcnt vmcnt(4)" ::: "memory");
      } else {
        asm volatile("s_waitcnt vmcnt(0)" ::: "memory");  // tail: tile 31
      }
      __builtin_amdgcn_sched_barrier(0);
      __builtin_amdgcn_s_barrier();  // tile it+1 visible to all waves
    }
  }

  // reduce l across the 4 g-groups (same q=li)
  l0 += __shfl_xor(l0, 16); l0 += __shfl_xor(l0, 32);
  l1 += __shfl_xor(l1, 16); l1 += __shfl_xor(l1, 32);
  const float inv0 = 1.0f / l0;
  const float inv1 = 1.0f / l1;

  __hip_bfloat16* cp = ctx + ((size_t)(b*2048 + qbase))*1024 + h*64;
  #pragma unroll
  for (int dt = 0; dt < 4; ++dt) {
    ushort4 o0, o1;
    o0.x = bf16_bits(acc0[dt][0] * inv0);
    o0.y = bf16_bits(acc0[dt][1] * inv0);
    o0.z = bf16_bits(acc0[dt][2] * inv0);
    o0.w = bf16_bits(acc0[dt][3] * inv0);
    *reinterpret_cast<ushort4*>(&cp[(size_t)li*1024 + dt*16 + g*4]) = o0;
    o1.x = bf16_bits(acc1[dt][0] * inv1);
    o1.y = bf16_bits(acc1[dt][1] * inv1);
    o1.z = bf16_bits(acc1[dt][2] * inv1);
    o1.w = bf16_bits(acc1[dt][3] * inv1);
    *reinterpret_cast<ushort4*>(&cp[(size_t)(16 + li)*1024 + dt*16 + g*4]) = o1;
  }
}

extern "C" void kernel_launch(void* const* d_in, const int* in_sizes, int n_in,
                              void* d_out, int out_size, void* d_ws, size_t ws_size,
                              hipStream_t stream)
{
  const float* x  = (const float*)d_in[0];
  const float* g  = (const float*)d_in[1];
  const float* be = (const float*)d_in[2];
  const float* Wq = (const float*)d_in[3];
  const float* bq = (const float*)d_in[4];
  const float* Wk = (const float*)d_in[5];
  const float* bk = (const float*)d_in[6];
  const float* Wv = (const float*)d_in[7];
  const float* bv = (const float*)d_in[8];
  const float* Wo = (const float*)d_in[9];
  const float* bo = (const float*)d_in[10];
  float* out = (float*)d_out;

  char* ws = (char*)d_ws;
  __hip_bfloat16* xn  = (__hip_bfloat16*)(ws);              // 16 MB
  __hip_bfloat16* Wqk = (__hip_bfloat16*)(ws + 16777216);   // 4 MB  [2048][1024]
  __hip_bfloat16* Wvb = (__hip_bfloat16*)(ws + 20971520);   // 2 MB
  __hip_bfloat16* Wob = (__hip_bfloat16*)(ws + 23068672);   // 2 MB
  __hip_bfloat16* Qb  = (__hip_bfloat16*)(ws + 25165824);   // 16 MB [bh][s][64]
  __hip_bfloat16* Kb  = (__hip_bfloat16*)(ws + 41943040);   // 16 MB
  __hip_bfloat16* Vt  = (__hip_bfloat16*)(ws + 58720256);   // 16 MB [1024][8192]
  __hip_bfloat16* ctx = (__hip_bfloat16*)(ws + 75497472);   // 16 MB [8192][1024]

  // LN + all weight converts in one dispatch
  prep_kernel<<<12288, 256, 0, stream>>>(x, g, be, xn, Wq, Wk, Wv, Wo, Wqk, Wvb, Wob);
  // Q,K projections + V^T in one dispatch (1536 blocks)
  qkv_gemm<<<1536, 256, 0, stream>>>(xn, Wqk, Wvb, bq, bk, bv, Qb, Kb, Vt);
  // attention
  attn_kernel<<<1024, 256, 0, stream>>>(Qb, Kb, Vt, ctx);
  // output projection: [8192 x 1024] = ctx @ Wo^T + bo (f32 out)
  out_gemm<<<dim3(8, 64), 256, 0, stream>>>(ctx, Wob, bo, out);
}

// Round 12
// 198.595 us; speedup vs baseline: 1.3004x; 1.1347x over previous
//
#include <hip/hip_runtime.h>
#include <hip/hip_bf16.h>
#include <stdint.h>

typedef __bf16 bf16x8 __attribute__((ext_vector_type(8)));
typedef float f32x4 __attribute__((ext_vector_type(4)));

#define LOG2E 1.44269504088896340736f

__device__ inline void gload_lds16(const void* g, void* l) {
  __builtin_amdgcn_global_load_lds((const __attribute__((address_space(1))) void*)g,
                                   (__attribute__((address_space(3))) void*)l, 16, 0, 0);
}

__device__ inline unsigned short bf16_bits(float f) {
  return __builtin_bit_cast(unsigned short, __float2bfloat16(f));
}

// raw v_exp_f32 (exp2f is a multi-instruction OCML call; scores are bounded
// so the bare instruction is exact enough)
__device__ inline float fast_exp2(float x) {
  return __builtin_amdgcn_exp2f(x);
}

// pack two f32 -> one u32 of 2 bf16 (low = first arg)
__device__ inline uint32_t cvtpk_bf16(float lo, float hi) {
  uint32_t d;
  asm("v_cvt_pk_bf16_f32 %0, %1, %2" : "=v"(d) : "v"(lo), "v"(hi));
  return d;
}
// gfx950 cross-lane row swaps
__device__ inline void plswap32(uint32_t& a, uint32_t& b) {
  asm("v_permlane32_swap_b32 %0, %1" : "+v"(a), "+v"(b));
}
__device__ inline void plswap16(uint32_t& a, uint32_t& b) {
  asm("v_permlane16_swap_b32 %0, %1" : "+v"(a), "+v"(b));
}

// ---------------- prep: LN (blocks 0..8191) + weight cvt (blocks 8192..12287) ----
__global__ __launch_bounds__(256) void prep_kernel(
    const float* __restrict__ x, const float* __restrict__ gamma,
    const float* __restrict__ beta, __hip_bfloat16* __restrict__ xn,
    const float* __restrict__ Wq, const float* __restrict__ Wk,
    const float* __restrict__ Wv, const float* __restrict__ Wo,
    __hip_bfloat16* __restrict__ Wqk, __hip_bfloat16* __restrict__ Wvb,
    __hip_bfloat16* __restrict__ Wob)
{
  const int t = threadIdx.x;
  if (blockIdx.x < 8192) {
    const int row = blockIdx.x;
    const float4 v = reinterpret_cast<const float4*>(x + (size_t)row * 1024)[t];
    float s = v.x + v.y + v.z + v.w;
    float q = v.x*v.x + v.y*v.y + v.z*v.z + v.w*v.w;
    #pragma unroll
    for (int off = 32; off >= 1; off >>= 1) {
      s += __shfl_xor(s, off);
      q += __shfl_xor(q, off);
    }
    __shared__ float ls[4], lq[4];
    const int wave = t >> 6, lane = t & 63;
    if (lane == 0) { ls[wave] = s; lq[wave] = q; }
    __syncthreads();
    s = ls[0] + ls[1] + ls[2] + ls[3];
    q = lq[0] + lq[1] + lq[2] + lq[3];
    const float mean = s * (1.0f/1024.0f);
    const float var  = q * (1.0f/1024.0f) - mean*mean;
    const float rstd = rsqrtf(var + 1e-6f);
    const float4 gm = reinterpret_cast<const float4*>(gamma)[t];
    const float4 bt = reinterpret_cast<const float4*>(beta)[t];
    ushort4 o;
    o.x = bf16_bits((v.x - mean)*rstd*gm.x + bt.x);
    o.y = bf16_bits((v.y - mean)*rstd*gm.y + bt.y);
    o.z = bf16_bits((v.z - mean)*rstd*gm.z + bt.z);
    o.w = bf16_bits((v.w - mean)*rstd*gm.w + bt.w);
    reinterpret_cast<ushort4*>(xn + (size_t)row*1024)[t] = o;
  } else {
    const int cb = blockIdx.x - 8192;        // 0..4095
    const int which = cb >> 10;              // 0..3
    const int i = (cb & 1023) * 256 + t;     // 0..1M-1
    const float* src;
    __hip_bfloat16* dst;
    if (which == 0)      { src = Wq; dst = Wqk; }
    else if (which == 1) { src = Wk; dst = Wqk + 1024*1024; }
    else if (which == 2) { src = Wv; dst = Wvb; }
    else                 { src = Wo; dst = Wob; }
    const float4 v = reinterpret_cast<const float4*>(src)[i];
    ushort4 o;
    o.x = bf16_bits(v.x); o.y = bf16_bits(v.y);
    o.z = bf16_bits(v.z); o.w = bf16_bits(v.w);
    reinterpret_cast<ushort4*>(dst)[i] = o;
  }
}

// ---------------- merged QKV NT-GEMM (gemm0: Q,K; gemm1: Vt) -------------------
// 1536 blocks: wg<1024 -> C=[Q;K] tiles (16x64); wg>=1024 -> Vt tiles (64x8).
// 128x128 tile, 4 waves, BK=32, K=1024, m97 structure (R8-proven).
__global__ __launch_bounds__(256) void qkv_gemm(
    const __hip_bfloat16* __restrict__ xn,
    const __hip_bfloat16* __restrict__ Wqk,
    const __hip_bfloat16* __restrict__ Wvb,
    const float* __restrict__ bq, const float* __restrict__ bk,
    const float* __restrict__ bv,
    __hip_bfloat16* __restrict__ Qb, __hip_bfloat16* __restrict__ Kb,
    __hip_bfloat16* __restrict__ Vt)
{
  constexpr int K = 1024;
  __shared__ __align__(16) __hip_bfloat16 Al[128*32];
  __shared__ __align__(16) __hip_bfloat16 Bl[128*32];
  const int t = threadIdx.x;
  const int wave = t >> 6, lane = t & 63;
  const int li = lane & 15, g = lane >> 4;
  const int wm = (wave >> 1) * 64, wn = (wave & 1) * 64;

  // XCD-bijective swizzle over 1536 blocks (192 per XCD)
  const int lin = blockIdx.x;
  const int wg  = (lin & 7) * 192 + (lin >> 3);
  const bool isV = wg >= 1024;
  int m0, n0;
  const __hip_bfloat16 *A, *B;
  if (!isV) {
    m0 = (wg >> 4) * 128; n0 = (wg & 15) * 128;   // A-panel shared across 16
    A = xn; B = Wqk;
  } else {
    const int w2 = wg - 1024;
    m0 = (w2 & 7) * 128; n0 = (w2 >> 3) * 128;    // B-panel shared across 8
    A = Wvb; B = xn;
  }
  const int srow = t >> 2, sch = (t & 3) * 8;

  const __hip_bfloat16* ga = A + (size_t)(m0 + srow) * K + sch;
  const __hip_bfloat16* gb = B + (size_t)(n0 + srow) * K + sch;

  f32x4 acc[4][4] = {};

  for (int kt = 0; kt < K; kt += 32) {
    gload_lds16(ga + kt,          Al + t*8);
    gload_lds16(ga + kt + 64*K,   Al + t*8 + 2048);
    gload_lds16(gb + kt,          Bl + t*8);
    gload_lds16(gb + kt + 64*K,   Bl + t*8 + 2048);
    __syncthreads();
    bf16x8 af[4], bfr[4];
    #pragma unroll
    for (int mi = 0; mi < 4; ++mi)
      af[mi] = *reinterpret_cast<const bf16x8*>(Al + (wm + mi*16 + li)*32 + g*8);
    #pragma unroll
    for (int ni = 0; ni < 4; ++ni)
      bfr[ni] = *reinterpret_cast<const bf16x8*>(Bl + (wn + ni*16 + li)*32 + g*8);
    #pragma unroll
    for (int mi = 0; mi < 4; ++mi)
      #pragma unroll
      for (int ni = 0; ni < 4; ++ni)
        acc[mi][ni] = __builtin_amdgcn_mfma_f32_16x16x32_bf16(af[mi], bfr[ni], acc[mi][ni], 0, 0, 0);
    __syncthreads();
  }

  #pragma unroll
  for (int mi = 0; mi < 4; ++mi) {
    #pragma unroll
    for (int ni = 0; ni < 4; ++ni) {
      #pragma unroll
      for (int r = 0; r < 4; ++r) {
        const int grow = m0 + wm + mi*16 + g*4 + r;
        const int gcol = n0 + wn + ni*16 + li;
        float v = acc[mi][ni][r];
        if (!isV) {
          const int b = grow >> 11, ss = grow & 2047;
          if (gcol < 1024) {
            // fold 1/sqrt(hd) AND log2(e) into Q so attn uses exp2 directly
            v = (v + bq[gcol]) * (0.125f * LOG2E);
            const int h = gcol >> 6, d = gcol & 63;
            Qb[(((size_t)(b*16 + h))*2048 + ss)*64 + d] = __float2bfloat16(v);
          } else {
            const int c2 = gcol - 1024;
            v = v + bk[c2];
            const int h = c2 >> 6, d = c2 & 63;
            Kb[(((size_t)(b*16 + h))*2048 + ss)*64 + d] = __float2bfloat16(v);
          }
        } else {
          v += bv[grow];
          Vt[(size_t)grow*8192 + gcol] = __float2bfloat16(v);
        }
      }
    }
  }
}

// ---------------- output projection NT-GEMM (R8-proven 128x128) ----------------
__global__ __launch_bounds__(256) void out_gemm(
    const __hip_bfloat16* __restrict__ A,
    const __hip_bfloat16* __restrict__ B,
    const float* __restrict__ bias,
    float* __restrict__ C)
{
  constexpr int K = 1024;
  __shared__ __align__(16) __hip_bfloat16 Al[128*32];
  __shared__ __align__(16) __hip_bfloat16 Bl[128*32];
  const int t = threadIdx.x;
  const int wave = t >> 6, lane = t & 63;
  const int li = lane & 15, g = lane >> 4;
  const int wm = (wave >> 1) * 64, wn = (wave & 1) * 64;

  const int lin = blockIdx.y * gridDim.x + blockIdx.x;
  const int cpx = (gridDim.x * gridDim.y) >> 3;
  const int wg  = (lin & 7) * cpx + (lin >> 3);
  const int bx  = wg & (gridDim.x - 1);
  const int by  = wg >> __builtin_ctz(gridDim.x);
  const int m0 = by * 128, n0 = bx * 128;
  const int srow = t >> 2, sch = (t & 3) * 8;

  const __hip_bfloat16* ga = A + (size_t)(m0 + srow) * K + sch;
  const __hip_bfloat16* gb = B + (size_t)(n0 + srow) * K + sch;

  f32x4 acc[4][4] = {};

  for (int kt = 0; kt < K; kt += 32) {
    gload_lds16(ga + kt,          Al + t*8);
    gload_lds16(ga + kt + 64*K,   Al + t*8 + 2048);
    gload_lds16(gb + kt,          Bl + t*8);
    gload_lds16(gb + kt + 64*K,   Bl + t*8 + 2048);
    __syncthreads();
    bf16x8 af[4], bfr[4];
    #pragma unroll
    for (int mi = 0; mi < 4; ++mi)
      af[mi] = *reinterpret_cast<const bf16x8*>(Al + (wm + mi*16 + li)*32 + g*8);
    #pragma unroll
    for (int ni = 0; ni < 4; ++ni)
      bfr[ni] = *reinterpret_cast<const bf16x8*>(Bl + (wn + ni*16 + li)*32 + g*8);
    #pragma unroll
    for (int mi = 0; mi < 4; ++mi)
      #pragma unroll
      for (int ni = 0; ni < 4; ++ni)
        acc[mi][ni] = __builtin_amdgcn_mfma_f32_16x16x32_bf16(af[mi], bfr[ni], acc[mi][ni], 0, 0, 0);
    __syncthreads();
  }

  #pragma unroll
  for (int mi = 0; mi < 4; ++mi) {
    #pragma unroll
    for (int ni = 0; ni < 4; ++ni) {
      #pragma unroll
      for (int r = 0; r < 4; ++r) {
        const int grow = m0 + wm + mi*16 + g*4 + r;
        const int gcol = n0 + wn + ni*16 + li;
        C[(size_t)grow*1024 + gcol] = acc[mi][ni][r] + bias[gcol];
      }
    }
  }
}

// ---------------- Flash attention (counted-vmcnt pipeline, in-register P) -------
// grid 1024 x 256 threads = 4 waves; wave owns 32 q-rows (2 x 16-row subtiles).
// Q pre-scaled by 0.125*log2(e); zero-max softmax p = v_exp_f32(s) directly.
// T4 schedule: raw s_barrier WAR sync, stage tile i+2, vmcnt(4), s_barrier.
// LDS = 32 KB -> 4 blocks/CU, grid = exactly 4 x 256 CU.
__global__ __launch_bounds__(256, 4) void attn_kernel(
    const __hip_bfloat16* __restrict__ Q,
    const __hip_bfloat16* __restrict__ K,
    const __hip_bfloat16* __restrict__ Vt,
    __hip_bfloat16* __restrict__ ctx)
{
  const int t = threadIdx.x, wave = t >> 6, lane = t & 63;
  const int li = lane & 15, g = lane >> 4;

  // XCD-chunked decode: 1024 blocks, 128 per XCD = 8 bh per XCD
  const int lin = blockIdx.x;
  const int wg  = (lin & 7) * 128 + (lin >> 3);
  const int bh  = wg >> 4, qt = wg & 15;
  const int b = bh >> 4, h = bh & 15;
  const int qbase = qt * 128 + wave * 32;

  __shared__ __align__(16) __hip_bfloat16 Klds[2][4096];  // 16 KB
  __shared__ __align__(16) __hip_bfloat16 Vlds[2][4096];  // 16 KB

  const bf16x8* Qv0 = reinterpret_cast<const bf16x8*>(Q + ((size_t)bh*2048 + qbase + li)*64 + g*8);
  const bf16x8* Qv1 = reinterpret_cast<const bf16x8*>(Q + ((size_t)bh*2048 + qbase + 16 + li)*64 + g*8);
  const bf16x8 aQ00 = Qv0[0], aQ01 = Qv0[4];
  const bf16x8 aQ10 = Qv1[0], aQ11 = Qv1[4];

  f32x4 acc0[4] = {}, acc1[4] = {};
  float l0 = 0.f, l1 = 0.f;

  const __hip_bfloat16* Kbh = K + (size_t)bh*2048*64;
  const __hip_bfloat16* Vbh = Vt + (size_t)h*64*8192 + b*2048;

  // staging geometry: swizzle byte ^= (row&7)<<4 pre-applied on GLOBAL source
  const int l8 = lane >> 3;
  const int scb_e = ((((lane & 7) * 16) ^ (l8 << 4)) >> 1);
  const int row0 = wave * 8 + l8;

  // ds_read offsets, swizzle applied on read
  const int krd0 = (li*128 + ((g*16)      ^ ((li & 7) << 4))) >> 1;
  const int krd1 = (li*128 + ((g*16 + 64) ^ ((li & 7) << 4))) >> 1;

  // prologue: stage tiles 0 and 1 (8 loads in flight/wave)
  gload_lds16(Kbh + (size_t)row0*64 + scb_e,          &Klds[0][wave*512]);
  gload_lds16(Kbh + (size_t)(32+row0)*64 + scb_e,     &Klds[0][2048 + wave*512]);
  gload_lds16(Vbh + (size_t)row0*8192 + scb_e,        &Vlds[0][wave*512]);
  gload_lds16(Vbh + (size_t)(32+row0)*8192 + scb_e,   &Vlds[0][2048 + wave*512]);
  gload_lds16(Kbh + (size_t)(64+row0)*64 + scb_e,     &Klds[1][wave*512]);
  gload_lds16(Kbh + (size_t)(96+row0)*64 + scb_e,     &Klds[1][2048 + wave*512]);
  gload_lds16(Vbh + (size_t)row0*8192 + 64 + scb_e,   &Vlds[1][wave*512]);
  gload_lds16(Vbh + (size_t)(32+row0)*8192 + 64 + scb_e, &Vlds[1][2048 + wave*512]);
  asm volatile("s_waitcnt vmcnt(4)" ::: "memory");  // tile 0 landed; tile 1 in flight
  __builtin_amdgcn_sched_barrier(0);
  __builtin_amdgcn_s_barrier();

  // loop staging starts at tile 2
  const __hip_bfloat16* kSrc = Kbh + (size_t)(128 + row0)*64 + scb_e;
  const __hip_bfloat16* vSrc = Vbh + (size_t)row0*8192 + 128 + scb_e;

  for (int it = 0; it < 32; ++it) {
    const int cur = it & 1;
    const __hip_bfloat16* Kc = Klds[cur];
    const __hip_bfloat16* Vc = Vlds[cur];

    // QK^T swapped, both subtiles per K-frag read
    f32x4 s0[4] = {}, s1[4] = {};
    __builtin_amdgcn_s_setprio(1);
    #pragma unroll
    for (int nt = 0; nt < 4; ++nt) {
      const bf16x8 k0 = *reinterpret_cast<const bf16x8*>(&Kc[nt*1024 + krd0]);
      const bf16x8 k1 = *reinterpret_cast<const bf16x8*>(&Kc[nt*1024 + krd1]);
      s0[nt] = __builtin_amdgcn_mfma_f32_16x16x32_bf16(k0, aQ00, s0[nt], 0, 0, 0);
      s0[nt] = __builtin_amdgcn_mfma_f32_16x16x32_bf16(k1, aQ01, s0[nt], 0, 0, 0);
      s1[nt] = __builtin_amdgcn_mfma_f32_16x16x32_bf16(k0, aQ10, s1[nt], 0, 0, 0);
      s1[nt] = __builtin_amdgcn_mfma_f32_16x16x32_bf16(k1, aQ11, s1[nt], 0, 0, 0);
    }
    __builtin_amdgcn_s_setprio(0);

    // zero-max softmax: p = v_exp_f32(s); per-lane partial l
    float sm0 = 0.f, sm1 = 0.f;
    #pragma unroll
    for (int nt = 0; nt < 4; ++nt)
      #pragma unroll
      for (int r = 0; r < 4; ++r) {
        const float p0 = fast_exp2(s0[nt][r]); s0[nt][r] = p0; sm0 += p0;
        const float p1 = fast_exp2(s1[nt][r]); s1[nt][r] = p1; sm1 += p1;
      }
    l0 += sm0; l1 += sm1;

    // in-register P redistribution (cvt_pk + permlane swaps)
    union U8 { uint32_t w[4]; bf16x8 v; };
    bf16x8 aP00, aP01, aP10, aP11;
    {
      uint32_t c[4][2];
      #pragma unroll
      for (int nt = 0; nt < 4; ++nt) {
        c[nt][0] = cvtpk_bf16(s0[nt][0], s0[nt][1]);
        c[nt][1] = cvtpk_bf16(s0[nt][2], s0[nt][3]);
      }
      uint32_t x0 = c[0][0], y0 = c[1][0], x1 = c[0][1], y1 = c[1][1];
      plswap32(x0, y0); plswap32(x1, y1);
      plswap16(x0, y0); plswap16(x1, y1);
      U8 u0; u0.w[0] = x0; u0.w[1] = x1; u0.w[2] = y0; u0.w[3] = y1;
      aP00 = u0.v;
      uint32_t x2 = c[2][0], y2 = c[3][0], x3 = c[2][1], y3 = c[3][1];
      plswap32(x2, y2); plswap32(x3, y3);
      plswap16(x2, y2); plswap16(x3, y3);
      U8 u1; u1.w[0] = x2; u1.w[1] = x3; u1.w[2] = y2; u1.w[3] = y3;
      aP01 = u1.v;
    }
    {
      uint32_t c[4][2];
      #pragma unroll
      for (int nt = 0; nt < 4; ++nt) {
        c[nt][0] = cvtpk_bf16(s1[nt][0], s1[nt][1]);
        c[nt][1] = cvtpk_bf16(s1[nt][2], s1[nt][3]);
      }
      uint32_t x0 = c[0][0], y0 = c[1][0], x1 = c[0][1], y1 = c[1][1];
      plswap32(x0, y0); plswap32(x1, y1);
      plswap16(x0, y0); plswap16(x1, y1);
      U8 u0; u0.w[0] = x0; u0.w[1] = x1; u0.w[2] = y0; u0.w[3] = y1;
      aP10 = u0.v;
      uint32_t x2 = c[2][0], y2 = c[3][0], x3 = c[2][1], y3 = c[3][1];
      plswap32(x2, y2); plswap32(x3, y3);
      plswap16(x2, y2); plswap16(x3, y3);
      U8 u1; u1.w[0] = x2; u1.w[1] = x3; u1.w[2] = y2; u1.w[3] = y3;
      aP11 = u1.v;
    }

    // PV swapped, both subtiles per V-frag read
    __builtin_amdgcn_s_setprio(1);
    #pragma unroll
    for (int dt = 0; dt < 4; ++dt) {
      const bf16x8 v0 = *reinterpret_cast<const bf16x8*>(&Vc[dt*1024 + krd0]);
      const bf16x8 v1 = *reinterpret_cast<const bf16x8*>(&Vc[dt*1024 + krd1]);
      acc0[dt] = __builtin_amdgcn_mfma_f32_16x16x32_bf16(v0, aP00, acc0[dt], 0, 0, 0);
      acc0[dt] = __builtin_amdgcn_mfma_f32_16x16x32_bf16(v1, aP01, acc0[dt], 0, 0, 0);
      acc1[dt] = __builtin_amdgcn_mfma_f32_16x16x32_bf16(v0, aP10, acc1[dt], 0, 0, 0);
      acc1[dt] = __builtin_amdgcn_mfma_f32_16x16x32_bf16(v1, aP11, acc1[dt], 0, 0, 0);
    }
    __builtin_amdgcn_s_setprio(0);

    if (it < 31) {
      // all waves done READING buf[cur]
      __builtin_amdgcn_s_barrier();
      if (it < 30) {
        gload_lds16(kSrc,           &Klds[cur][wave*512]);
        gload_lds16(kSrc + 32*64,   &Klds[cur][2048 + wave*512]);
        gload_lds16(vSrc,           &Vlds[cur][wave*512]);
        gload_lds16(vSrc + 32*8192, &Vlds[cur][2048 + wave*512]);
        kSrc += 64*64;
        vSrc += 64;
        asm volatile("s_waitcnt vmcnt(4)" ::: "memory");
      } else {
        asm volatile("s_waitcnt vmcnt(0)" ::: "memory");
      }
      __builtin_amdgcn_sched_barrier(0);
      __builtin_amdgcn_s_barrier();
    }
  }

  // reduce l across the 4 g-groups (same q=li)
  l0 += __shfl_xor(l0, 16); l0 += __shfl_xor(l0, 32);
  l1 += __shfl_xor(l1, 16); l1 += __shfl_xor(l1, 32);
  const float inv0 = 1.0f / l0;
  const float inv1 = 1.0f / l1;

  __hip_bfloat16* cp = ctx + ((size_t)(b*2048 + qbase))*1024 + h*64;
  #pragma unroll
  for (int dt = 0; dt < 4; ++dt) {
    ushort4 o0, o1;
    o0.x = bf16_bits(acc0[dt][0] * inv0);
    o0.y = bf16_bits(acc0[dt][1] * inv0);
    o0.z = bf16_bits(acc0[dt][2] * inv0);
    o0.w = bf16_bits(acc0[dt][3] * inv0);
    *reinterpret_cast<ushort4*>(&cp[(size_t)li*1024 + dt*16 + g*4]) = o0;
    o1.x = bf16_bits(acc1[dt][0] * inv1);
    o1.y = bf16_bits(acc1[dt][1] * inv1);
    o1.z = bf16_bits(acc1[dt][2] * inv1);
    o1.w = bf16_bits(acc1[dt][3] * inv1);
    *reinterpret_cast<ushort4*>(&cp[(size_t)(16 + li)*1024 + dt*16 + g*4]) = o1;
  }
}

extern "C" void kernel_launch(void* const* d_in, const int* in_sizes, int n_in,
                              void* d_out, int out_size, void* d_ws, size_t ws_size,
                              hipStream_t stream)
{
  const float* x  = (const float*)d_in[0];
  const float* g  = (const float*)d_in[1];
  const float* be = (const float*)d_in[2];
  const float* Wq = (const float*)d_in[3];
  const float* bq = (const float*)d_in[4];
  const float* Wk = (const float*)d_in[5];
  const float* bk = (const float*)d_in[6];
  const float* Wv = (const float*)d_in[7];
  const float* bv = (const float*)d_in[8];
  const float* Wo = (const float*)d_in[9];
  const float* bo = (const float*)d_in[10];
  float* out = (float*)d_out;

  char* ws = (char*)d_ws;
  __hip_bfloat16* xn  = (__hip_bfloat16*)(ws);              // 16 MB
  __hip_bfloat16* Wqk = (__hip_bfloat16*)(ws + 16777216);   // 4 MB  [2048][1024]
  __hip_bfloat16* Wvb = (__hip_bfloat16*)(ws + 20971520);   // 2 MB
  __hip_bfloat16* Wob = (__hip_bfloat16*)(ws + 23068672);   // 2 MB
  __hip_bfloat16* Qb  = (__hip_bfloat16*)(ws + 25165824);   // 16 MB [bh][s][64]
  __hip_bfloat16* Kb  = (__hip_bfloat16*)(ws + 41943040);   // 16 MB
  __hip_bfloat16* Vt  = (__hip_bfloat16*)(ws + 58720256);   // 16 MB [1024][8192]
  __hip_bfloat16* ctx = (__hip_bfloat16*)(ws + 75497472);   // 16 MB [8192][1024]

  // LN + all weight converts in one dispatch
  prep_kernel<<<12288, 256, 0, stream>>>(x, g, be, xn, Wq, Wk, Wv, Wo, Wqk, Wvb, Wob);
  // Q,K projections + V^T in one dispatch (1536 blocks)
  qkv_gemm<<<1536, 256, 0, stream>>>(xn, Wqk, Wvb, bq, bk, bv, Qb, Kb, Vt);
  // attention
  attn_kernel<<<1024, 256, 0, stream>>>(Qb, Kb, Vt, ctx);
  // output projection: [8192 x 1024] = ctx @ Wo^T + bo (f32 out)
  out_gemm<<<dim3(8, 64), 256, 0, stream>>>(ctx, Wob, bo, out);
}